// Round 8
// baseline (366.860 us; speedup 1.0000x reference)
//
#include <hip/hip_runtime.h>
#include <hip/hip_bf16.h>
#include <math.h>

#define Bn 64
#define Sn 512
#define Hn 1024
#define Tn 48

#define LOG2E 1.4426950408889634f
#define LN2f  0.6931471805599453f

#define PRED_OFF (Bn*Sn*Tn)
#define LOSS_OFF (PRED_OFF + Bn*Sn)

#define RL(x,i) __int_as_float(__builtin_amdgcn_readlane(__float_as_int(x),(i)))

#if __has_builtin(__builtin_amdgcn_exp2f)
#define EXP2(x) __builtin_amdgcn_exp2f(x)
#else
#define EXP2(x) exp2f(x)
#endif
#if __has_builtin(__builtin_amdgcn_logf)
#define LOG2(x) __builtin_amdgcn_logf(x)
#else
#define LOG2(x) log2f(x)
#endif

__device__ __forceinline__ unsigned umin2(unsigned a, unsigned b) { return a < b ? a : b; }

// workspace layout (bytes): [0,256) logZ, [256,512) gold, [512, +6291456) v-values,
// then 1572864 bytes of backpointers.
#define VWS_BYTE_OFF 512
#define BPW_BYTE_OFF (512 + (size_t)Bn*Sn*Tn*4)
#define WS_NEED (BPW_BYTE_OFF + (size_t)Bn*Sn*Tn)

// ======================= GEMM: feat = x @ W + b (R4 config, measured best) ===
#define DOT4(ACC,A,B) { ACC = fmaf((A).x,(B).x,ACC); ACC = fmaf((A).y,(B).y,ACC); ACC = fmaf((A).z,(B).z,ACC); ACC = fmaf((A).w,(B).w,ACC); }

__global__ __launch_bounds__(256) void gemm_feat(
    const float* __restrict__ x, const float* __restrict__ W,
    const float* __restrict__ bias, float* __restrict__ feat)
{
  __shared__ __align__(16) float xs[64][68];
  __shared__ __align__(16) float wsT[Tn][68];
  const int tid = threadIdx.x;
  const int srow = tid >> 2;
  const int sqc  = tid & 3;
  const int ty = tid >> 3;
  const int tx = tid & 7;
  const size_t row0 = (size_t)blockIdx.x * 64;

  float4 xreg[4];
  float  wreg[12];
  #pragma unroll
  for (int p = 0; p < 4; ++p)
    xreg[p] = *reinterpret_cast<const float4*>(&x[(row0 + srow)*Hn + (sqc + p*4)*4]);
  #pragma unroll
  for (int i = 0; i < 12; ++i) {
    const int id = tid + i*256; const int kk = id/Tn; const int t = id - kk*Tn;
    wreg[i] = W[(size_t)kk*Tn + t];
  }

  float acc[2][6];
  #pragma unroll
  for (int r = 0; r < 2; ++r)
    #pragma unroll
    for (int c = 0; c < 6; ++c) acc[r][c] = 0.f;

  for (int k0 = 0; k0 < Hn; k0 += 64) {
    #pragma unroll
    for (int p = 0; p < 4; ++p)
      *reinterpret_cast<float4*>(&xs[srow][(sqc + p*4)*4]) = xreg[p];
    #pragma unroll
    for (int i = 0; i < 12; ++i) {
      const int id = tid + i*256; const int kk = id/Tn; const int t = id - kk*Tn;
      wsT[t][kk] = wreg[i];
    }
    __syncthreads();
    if (k0 + 64 < Hn) {
      #pragma unroll
      for (int p = 0; p < 4; ++p)
        xreg[p] = *reinterpret_cast<const float4*>(&x[(row0 + srow)*Hn + (k0+64) + (sqc + p*4)*4]);
      #pragma unroll
      for (int i = 0; i < 12; ++i) {
        const int id = tid + i*256; const int kk = id/Tn; const int t = id - kk*Tn;
        wreg[i] = W[(size_t)(k0 + 64 + kk)*Tn + t];
      }
    }
    #pragma unroll 4
    for (int kk = 0; kk < 64; kk += 4) {
      const float4 a0 = *reinterpret_cast<const float4*>(&xs[ty*2+0][kk]);
      const float4 a1 = *reinterpret_cast<const float4*>(&xs[ty*2+1][kk]);
      const float4 w0 = *reinterpret_cast<const float4*>(&wsT[tx*6+0][kk]);
      const float4 w1 = *reinterpret_cast<const float4*>(&wsT[tx*6+1][kk]);
      const float4 w2 = *reinterpret_cast<const float4*>(&wsT[tx*6+2][kk]);
      const float4 w3 = *reinterpret_cast<const float4*>(&wsT[tx*6+3][kk]);
      const float4 w4 = *reinterpret_cast<const float4*>(&wsT[tx*6+4][kk]);
      const float4 w5 = *reinterpret_cast<const float4*>(&wsT[tx*6+5][kk]);
      DOT4(acc[0][0],a0,w0) DOT4(acc[0][1],a0,w1) DOT4(acc[0][2],a0,w2)
      DOT4(acc[0][3],a0,w3) DOT4(acc[0][4],a0,w4) DOT4(acc[0][5],a0,w5)
      DOT4(acc[1][0],a1,w0) DOT4(acc[1][1],a1,w1) DOT4(acc[1][2],a1,w2)
      DOT4(acc[1][3],a1,w3) DOT4(acc[1][4],a1,w4) DOT4(acc[1][5],a1,w5)
    }
    __syncthreads();
  }
  #pragma unroll
  for (int c = 0; c < 6; ++c) {
    const int col = tx*6 + c;
    const float bv = bias[col];
    #pragma unroll
    for (int r = 0; r < 2; ++r)
      feat[(row0 + ty*2 + r)*Tn + col] = acc[r][c] + bv;
  }
}

// ============ helper: sequence length (prefix mask) per wave ============
__device__ __forceinline__ int seq_len(const int* __restrict__ mask, int b, int lane) {
  int lc = 0;
  #pragma unroll
  for (int it = 0; it < Sn/64; ++it) lc += (mask[(size_t)b*Sn + it*64 + lane] != 0);
  #pragma unroll
  for (int off = 32; off; off >>= 1) lc += __shfl_xor(lc, off);
  return lc;
}

// ======================= crf_scan: 192 single-wave blocks =======================
// role 0: log-partition (pure-register readlane matvec)
// role 1: Viterbi VALUE forward only (readlane + max3 tree; stores v to ws)
// role 2: gold score
__global__ __launch_bounds__(64, 1) void crf_scan(
    const float* __restrict__ feat,
    const int* __restrict__ mask,
    const int* __restrict__ labels,
    const float* __restrict__ trans,
    const float* __restrict__ startv,
    const float* __restrict__ endv,
    float* __restrict__ vws,
    float* __restrict__ wsLogZ,
    float* __restrict__ wsGold)
{
  const int role = blockIdx.x >> 6;
  const int b    = blockIdx.x & 63;
  const int lane = threadIdx.x;
  const float* fb = feat + (size_t)b * Sn * Tn;
  const int len = seq_len(mask, b, lane);
  const int j = (lane < Tn) ? lane : (Tn - 1);

  if (role == 0) {
    // ---------------- log-partition (registers only) ----------------
    float Ev[48];
    #pragma unroll
    for (int i = 0; i < 48; ++i) Ev[i] = EXP2(trans[i*Tn + j] * LOG2E);
    float emq[8];
    #pragma unroll
    for (int d = 0; d < 8; ++d) {
      int s = 1 + d; s = s < len ? s : len - 1;
      emq[d] = fb[(size_t)s * Tn + j];
    }
    const float a0 = (startv[j] + fb[j]) * LOG2E;
    float Zref = RL(a0, 0);
    float beta = a0 - Zref;
    float p = EXP2(beta);
    for (int t = 1; t < len; t += 8) {
      #pragma unroll
      for (int u = 0; u < 8; ++u) {
        const int tt = t + u;
        if (tt < len) {
          const float em2 = emq[u] * LOG2E;
          int tf = tt + 8; tf = tf < len ? tf : len - 1;
          emq[u] = fb[(size_t)tf * Tn + j];
          float s0=0.f, s1=0.f, s2=0.f, s3=0.f;
          #pragma unroll
          for (int k = 0; k < 12; ++k) {
            s0 = fmaf(RL(p, 4*k+0), Ev[4*k+0], s0);
            s1 = fmaf(RL(p, 4*k+1), Ev[4*k+1], s1);
            s2 = fmaf(RL(p, 4*k+2), Ev[4*k+2], s2);
            s3 = fmaf(RL(p, 4*k+3), Ev[4*k+3], s3);
          }
          const float dj = LOG2((s0 + s1) + (s2 + s3)) + em2;
          const float d0 = RL(dj, 0);
          Zref += d0;
          beta = dj - d0;
          p = EXP2(beta);
        }
      }
    }
    float fv = (lane < Tn) ? beta + endv[lane] * LOG2E : -INFINITY;
    float m = fv;
    #pragma unroll
    for (int off = 32; off; off >>= 1) m = fmaxf(m, __shfl_xor(m, off));
    float e = (lane < Tn) ? EXP2(fv - m) : 0.f;
    #pragma unroll
    for (int off = 32; off; off >>= 1) e += __shfl_xor(e, off);
    if (lane == 0) wsLogZ[b] = (Zref + m + LOG2(e)) * LN2f;

  } else if (role == 1) {
    // ---------------- Viterbi value forward (no index) ----------------
    float trv[48];
    #pragma unroll
    for (int i = 0; i < 48; ++i) trv[i] = trans[i*Tn + j];
    float emq[8];
    #pragma unroll
    for (int d = 0; d < 8; ++d) {
      int s = 1 + d; s = s < len ? s : len - 1;
      emq[d] = fb[(size_t)s * Tn + j];
    }
    float v = startv[j] + fb[j];
    if (lane < Tn) vws[(size_t)b*Sn*Tn + lane] = v;
    for (int t = 1; t < len; t += 8) {
      #pragma unroll
      for (int u = 0; u < 8; ++u) {
        const int tt = t + u;
        if (tt < len) {
          const float em_cur = emq[u];
          int tf = tt + 8; tf = tf < len ? tf : len - 1;
          emq[u] = fb[(size_t)tf * Tn + j];
          float q[48];
          #pragma unroll
          for (int i = 0; i < 48; ++i) q[i] = RL(v, i) + trv[i];
          float m16[16];
          #pragma unroll
          for (int uu = 0; uu < 16; ++uu)
            m16[uu] = fmaxf(fmaxf(q[3*uu], q[3*uu+1]), q[3*uu+2]);
          float m6a = fmaxf(fmaxf(m16[0],  m16[1]),  m16[2]);
          float m6b = fmaxf(fmaxf(m16[3],  m16[4]),  m16[5]);
          float m6c = fmaxf(fmaxf(m16[6],  m16[7]),  m16[8]);
          float m6d = fmaxf(fmaxf(m16[9],  m16[10]), m16[11]);
          float m6e = fmaxf(fmaxf(m16[12], m16[13]), m16[14]);
          const float best = fmaxf(fmaxf(fmaxf(m6a,m6b),m6c),
                                   fmaxf(fmaxf(m6d,m6e),m16[15]));
          v = best + em_cur;
          if (lane < Tn) vws[((size_t)b*Sn + tt)*Tn + lane] = v;
        }
      }
    }

  } else {
    // ---------------- gold score ----------------
    float g = 0.f;
    #pragma unroll
    for (int it = 0; it < Sn/64; ++it) {
      const int sg = it*64 + lane;
      if (sg < len) {
        const int la = labels[(size_t)b*Sn + sg];
        float e = fb[(size_t)sg*Tn + la];
        if (sg > 0) e += trans[labels[(size_t)b*Sn + sg - 1]*Tn + la];
        g += e;
      }
    }
    #pragma unroll
    for (int off = 32; off; off >>= 1) g += __shfl_xor(g, off);
    if (lane == 0) {
      g += startv[labels[(size_t)b*Sn]] + endv[labels[(size_t)b*Sn + len - 1]];
      wsGold[b] = g;
    }
  }
}

// ======================= bp_kernel: parallel backpointers =======================
// grid 512 blocks x 256 thr; block (b, oct): 4 waves x 16 t each.
// bp[t][j] = first-occurrence argmax_i (v[t-1][i] + trans[i][j]); independent over (b,t).
__global__ __launch_bounds__(256) void bp_kernel(
    const float* __restrict__ vws,
    const int* __restrict__ mask,
    const float* __restrict__ trans,
    unsigned char* __restrict__ bpw)
{
  const int b    = blockIdx.x >> 3;
  const int oct  = blockIdx.x & 7;
  const int wv   = threadIdx.x >> 6;
  const int lane = threadIdx.x & 63;
  const int len = seq_len(mask, b, lane);
  const int j = (lane < Tn) ? lane : (Tn - 1);

  float trv[48];
  #pragma unroll
  for (int i = 0; i < 48; ++i) trv[i] = trans[i*Tn + j];

  const int t0 = oct*64 + wv*16;
  #pragma unroll 2
  for (int i = 0; i < 16; ++i) {
    const int t = t0 + i;
    int te = t; te = te < 1 ? 1 : te; te = te < len ? te : len - 1;
    const float4* vp = reinterpret_cast<const float4*>(vws + ((size_t)b*Sn + te - 1)*Tn);
    float q[48];
    #pragma unroll
    for (int k = 0; k < 12; ++k) {
      const float4 a = vp[k];
      q[4*k+0] = a.x + trv[4*k+0];
      q[4*k+1] = a.y + trv[4*k+1];
      q[4*k+2] = a.z + trv[4*k+2];
      q[4*k+3] = a.w + trv[4*k+3];
    }
    float m16[16];
    #pragma unroll
    for (int u = 0; u < 16; ++u)
      m16[u] = fmaxf(fmaxf(q[3*u], q[3*u+1]), q[3*u+2]);
    float m6a = fmaxf(fmaxf(m16[0],  m16[1]),  m16[2]);
    float m6b = fmaxf(fmaxf(m16[3],  m16[4]),  m16[5]);
    float m6c = fmaxf(fmaxf(m16[6],  m16[7]),  m16[8]);
    float m6d = fmaxf(fmaxf(m16[9],  m16[10]), m16[11]);
    float m6e = fmaxf(fmaxf(m16[12], m16[13]), m16[14]);
    const float best = fmaxf(fmaxf(fmaxf(m6a,m6b),m6c),
                             fmaxf(fmaxf(m6d,m6e),m16[15]));
    unsigned s16[16];
    #pragma unroll
    for (int u = 0; u < 16; ++u) {
      const unsigned ka = __float_as_uint(q[3*u]   - best) | (unsigned)(3*u);
      const unsigned kb = __float_as_uint(q[3*u+1] - best) | (unsigned)(3*u+1);
      const unsigned kc = __float_as_uint(q[3*u+2] - best) | (unsigned)(3*u+2);
      s16[u] = umin2(umin2(ka, kb), kc);
    }
    unsigned i6a = umin2(umin2(s16[0],  s16[1]),  s16[2]);
    unsigned i6b = umin2(umin2(s16[3],  s16[4]),  s16[5]);
    unsigned i6c = umin2(umin2(s16[6],  s16[7]),  s16[8]);
    unsigned i6d = umin2(umin2(s16[9],  s16[10]), s16[11]);
    unsigned i6e = umin2(umin2(s16[12], s16[13]), s16[14]);
    const unsigned bidx = umin2(umin2(umin2(i6a,i6b),i6c), umin2(umin2(i6d,i6e),s16[15]));
    if (t >= 1 && t < len && lane < Tn)
      bpw[((size_t)b*Sn + t)*Tn + lane] = (unsigned char)bidx;
  }
}

// ======================= backtrace kernel =======================
__device__ __forceinline__ unsigned idw(int a) {
  return (unsigned)a | ((unsigned)(a+1)<<8) | ((unsigned)(a+2)<<16) | ((unsigned)(a+3)<<24);
}

__global__ __launch_bounds__(64, 1) void backtrace_kernel(
    const float* __restrict__ vws,
    const unsigned char* __restrict__ bpw,
    const int* __restrict__ mask,
    const float* __restrict__ endv,
    float* __restrict__ pred_out)
{
  __shared__ unsigned char bpL[Sn * Tn];     // 24 KB, stride 48
  __shared__ unsigned char pathL[384 * 64];  // 24 KB
  __shared__ int EA[8];

  const int b    = blockIdx.x;
  const int lane = threadIdx.x;
  const int len = seq_len(mask, b, lane);

  // load backpointers (identity for t==0 and t>=len)
  {
    const uint4* gb = reinterpret_cast<const uint4*>(bpw + (size_t)b*Sn*Tn);
    uint4* bl = reinterpret_cast<uint4*>(bpL);
    for (int i4 = lane; i4 < Sn*Tn/16; i4 += 64) {
      const int byte0 = i4*16;
      const int t = byte0 / Tn;
      const int j0 = byte0 - t*Tn;
      uint4 val;
      if (t >= 1 && t < len) val = gb[i4];
      else { val.x = idw(j0); val.y = idw(j0+4); val.z = idw(j0+8); val.w = idw(j0+12); }
      bl[i4] = val;
    }
  }

  // final first-occurrence argmax over v[len-1] + end
  float fv = (lane < Tn) ? vws[((size_t)b*Sn + len - 1)*Tn + lane] + endv[lane] : -INFINITY;
  int fi = (lane < Tn) ? lane : 64;
  #pragma unroll
  for (int off = 32; off; off >>= 1) {
    const float ov = __shfl_xor(fv, off);
    const int   oi = __shfl_xor(fi, off);
    if (ov > fv || (ov == fv && oi < fi)) { fv = ov; fi = oi; }
  }
  __syncthreads();

  // segment-parallel backtrace: 8 segments x 48 entry tags = 384 jobs, 6 chains/lane
  #define JOB(r) \
    const int id##r  = lane + 64*(r); \
    const int seg##r = id##r & 7;     \
    int cur##r = id##r >> 3;          \
    const int bpb##r = seg##r * 64 * Tn; \
    const int pb##r  = id##r << 6;    \
    pathL[pb##r + 63] = (unsigned char)cur##r;
  JOB(0) JOB(1) JOB(2) JOB(3) JOB(4) JOB(5)
  for (int d = 62; d >= 0; --d) {
    const int o = (d + 1) * Tn;
    cur0 = bpL[bpb0 + o + cur0]; pathL[pb0 + d] = (unsigned char)cur0;
    cur1 = bpL[bpb1 + o + cur1]; pathL[pb1 + d] = (unsigned char)cur1;
    cur2 = bpL[bpb2 + o + cur2]; pathL[pb2 + d] = (unsigned char)cur2;
    cur3 = bpL[bpb3 + o + cur3]; pathL[pb3 + d] = (unsigned char)cur3;
    cur4 = bpL[bpb4 + o + cur4]; pathL[pb4 + d] = (unsigned char)cur4;
    cur5 = bpL[bpb5 + o + cur5]; pathL[pb5 + d] = (unsigned char)cur5;
  }
  #undef JOB
  __syncthreads();
  if (lane == 0) {
    int Ecur = fi;
    EA[7] = Ecur;
    for (int s = 7; s >= 1; --s) {
      const int bottom = pathL[((Ecur << 3) + s) * 64];
      Ecur = bpL[(s * 64) * Tn + bottom];
      EA[s-1] = Ecur;
    }
  }
  __syncthreads();
  #pragma unroll
  for (int r8 = 0; r8 < 8; ++r8) {
    const int t = r8*64 + lane;
    const int pv = pathL[((EA[r8] << 3) + r8) * 64 + lane];
    pred_out[(size_t)b*Sn + t] = (t < len) ? (float)pv : 0.f;
  }
}

// ======================= fallback (R7 full kernel) =======================
__global__ __launch_bounds__(64, 1) void crf_kernel_fb(
    const float* __restrict__ feat,
    const int* __restrict__ mask,
    const int* __restrict__ labels,
    const float* __restrict__ trans,
    const float* __restrict__ startv,
    const float* __restrict__ endv,
    float* __restrict__ pred_out,
    float* __restrict__ wsLogZ,
    float* __restrict__ wsGold)
{
  __shared__ unsigned char bpL[Sn * 64];
  __shared__ unsigned char pathL[384 * 64];
  __shared__ __align__(16) float slds[64];
  __shared__ int EA[8];

  const int role = blockIdx.x >> 6;
  const int b    = blockIdx.x & 63;
  const int lane = threadIdx.x;
  const float* fb = feat + (size_t)b * Sn * Tn;
  const int len = seq_len(mask, b, lane);
  const int j = (lane < Tn) ? lane : (Tn - 1);
  const float4* sv4 = reinterpret_cast<const float4*>(slds);

  if (role == 0) {
    float Ev[48];
    #pragma unroll
    for (int i = 0; i < 48; ++i) Ev[i] = EXP2(trans[i*Tn + j] * LOG2E);
    const float a0 = (startv[j] + fb[j]) * LOG2E;
    float Zref = RL(a0, 0);
    float beta = a0 - Zref;
    slds[lane] = EXP2(beta);
    float em2 = fb[Tn + j] * LOG2E;
    for (int t = 1; t < len; ++t) {
      const int tn = (t + 1 < len) ? (t + 1) : t;
      const float em_nxt = fb[(size_t)tn*Tn + j] * LOG2E;
      float4 av[12];
      #pragma unroll
      for (int k = 0; k < 12; ++k) av[k] = sv4[k];
      float s0=0.f, s1=0.f, s2=0.f, s3=0.f;
      #pragma unroll
      for (int k = 0; k < 12; ++k) {
        s0 = fmaf(av[k].x, Ev[4*k+0], s0);
        s1 = fmaf(av[k].y, Ev[4*k+1], s1);
        s2 = fmaf(av[k].z, Ev[4*k+2], s2);
        s3 = fmaf(av[k].w, Ev[4*k+3], s3);
      }
      const float dj = LOG2((s0 + s1) + (s2 + s3)) + em2;
      const float d0 = RL(dj, 0);
      Zref += d0;
      const float nb = dj - d0;
      slds[lane] = EXP2(nb);
      beta = nb;
      em2 = em_nxt;
    }
    float fv = (lane < Tn) ? beta + endv[lane] * LOG2E : -INFINITY;
    float m = fv;
    #pragma unroll
    for (int off = 32; off; off >>= 1) m = fmaxf(m, __shfl_xor(m, off));
    float e = (lane < Tn) ? EXP2(fv - m) : 0.f;
    #pragma unroll
    for (int off = 32; off; off >>= 1) e += __shfl_xor(e, off);
    if (lane == 0) wsLogZ[b] = (Zref + m + LOG2(e)) * LN2f;

  } else if (role == 1) {
    float trv[48];
    #pragma unroll
    for (int i = 0; i < 48; ++i) trv[i] = trans[i*Tn + j];
    float v = startv[j] + fb[j];
    slds[lane] = v;
    float em_cur = fb[Tn + j];
    for (int t = 1; t < len; ++t) {
      const int tn = (t + 1 < len) ? (t + 1) : t;
      const float em_nxt = fb[(size_t)tn*Tn + j];
      float4 av[12];
      #pragma unroll
      for (int k = 0; k < 12; ++k) av[k] = sv4[k];
      float q[48];
      #pragma unroll
      for (int k = 0; k < 12; ++k) {
        q[4*k+0] = av[k].x + trv[4*k+0];
        q[4*k+1] = av[k].y + trv[4*k+1];
        q[4*k+2] = av[k].z + trv[4*k+2];
        q[4*k+3] = av[k].w + trv[4*k+3];
      }
      float m16[16];
      #pragma unroll
      for (int uu = 0; uu < 16; ++uu)
        m16[uu] = fmaxf(fmaxf(q[3*uu], q[3*uu+1]), q[3*uu+2]);
      float m6a = fmaxf(fmaxf(m16[0],  m16[1]),  m16[2]);
      float m6b = fmaxf(fmaxf(m16[3],  m16[4]),  m16[5]);
      float m6c = fmaxf(fmaxf(m16[6],  m16[7]),  m16[8]);
      float m6d = fmaxf(fmaxf(m16[9],  m16[10]), m16[11]);
      float m6e = fmaxf(fmaxf(m16[12], m16[13]), m16[14]);
      const float best = fmaxf(fmaxf(fmaxf(m6a,m6b),m6c),
                               fmaxf(fmaxf(m6d,m6e),m16[15]));
      v = best + em_cur;
      slds[lane] = v;
      unsigned s16[16];
      #pragma unroll
      for (int uu = 0; uu < 16; ++uu) {
        const unsigned ka = __float_as_uint(q[3*uu]   - best) | (unsigned)(3*uu);
        const unsigned kb = __float_as_uint(q[3*uu+1] - best) | (unsigned)(3*uu+1);
        const unsigned kc = __float_as_uint(q[3*uu+2] - best) | (unsigned)(3*uu+2);
        s16[uu] = umin2(umin2(ka, kb), kc);
      }
      unsigned i6a = umin2(umin2(s16[0],  s16[1]),  s16[2]);
      unsigned i6b = umin2(umin2(s16[3],  s16[4]),  s16[5]);
      unsigned i6c = umin2(umin2(s16[6],  s16[7]),  s16[8]);
      unsigned i6d = umin2(umin2(s16[9],  s16[10]), s16[11]);
      unsigned i6e = umin2(umin2(s16[12], s16[13]), s16[14]);
      const unsigned bidx = umin2(umin2(umin2(i6a,i6b),i6c), umin2(umin2(i6d,i6e),s16[15]));
      bpL[t*64 + lane] = (unsigned char)bidx;
      em_cur = em_nxt;
    }
    for (int t = len; t < Sn; ++t) bpL[t*64 + lane] = (unsigned char)lane;
    float fv = (lane < Tn) ? v + endv[lane] : -INFINITY;
    int fi = (lane < Tn) ? lane : 64;
    #pragma unroll
    for (int off = 32; off; off >>= 1) {
      const float ov = __shfl_xor(fv, off);
      const int   oi = __shfl_xor(fi, off);
      if (ov > fv || (ov == fv && oi < fi)) { fv = ov; fi = oi; }
    }
    __syncthreads();
    #define JOBF(r) \
      const int id##r  = lane + 64*(r); \
      const int seg##r = id##r & 7;     \
      int cur##r = id##r >> 3;          \
      const int bpb##r = seg##r << 12;  \
      const int pb##r  = id##r << 6;    \
      pathL[pb##r + 63] = (unsigned char)cur##r;
    JOBF(0) JOBF(1) JOBF(2) JOBF(3) JOBF(4) JOBF(5)
    for (int d = 62; d >= 0; --d) {
      const int o = (d + 1) << 6;
      cur0 = bpL[bpb0 + o + cur0]; pathL[pb0 + d] = (unsigned char)cur0;
      cur1 = bpL[bpb1 + o + cur1]; pathL[pb1 + d] = (unsigned char)cur1;
      cur2 = bpL[bpb2 + o + cur2]; pathL[pb2 + d] = (unsigned char)cur2;
      cur3 = bpL[bpb3 + o + cur3]; pathL[pb3 + d] = (unsigned char)cur3;
      cur4 = bpL[bpb4 + o + cur4]; pathL[pb4 + d] = (unsigned char)cur4;
      cur5 = bpL[bpb5 + o + cur5]; pathL[pb5 + d] = (unsigned char)cur5;
    }
    #undef JOBF
    __syncthreads();
    if (lane == 0) {
      int Ecur = fi;
      EA[7] = Ecur;
      for (int s = 7; s >= 1; --s) {
        const int bottom = pathL[((Ecur << 3) + s) * 64];
        Ecur = bpL[(s << 12) + bottom];
        EA[s-1] = Ecur;
      }
    }
    __syncthreads();
    #pragma unroll
    for (int r8 = 0; r8 < 8; ++r8) {
      const int t = r8*64 + lane;
      const int pv = pathL[((EA[r8] << 3) + r8) * 64 + lane];
      pred_out[(size_t)b*Sn + t] = (t < len) ? (float)pv : 0.f;
    }
  } else {
    float g = 0.f;
    #pragma unroll
    for (int it = 0; it < Sn/64; ++it) {
      const int sg = it*64 + lane;
      if (sg < len) {
        const int la = labels[(size_t)b*Sn + sg];
        float e = fb[(size_t)sg*Tn + la];
        if (sg > 0) e += trans[labels[(size_t)b*Sn + sg - 1]*Tn + la];
        g += e;
      }
    }
    #pragma unroll
    for (int off = 32; off; off >>= 1) g += __shfl_xor(g, off);
    if (lane == 0) {
      g += startv[labels[(size_t)b*Sn]] + endv[labels[(size_t)b*Sn + len - 1]];
      wsGold[b] = g;
    }
  }
}

__global__ void loss_reduce(const float* __restrict__ wsLogZ,
                            const float* __restrict__ wsGold,
                            float* __restrict__ out)
{
  const int lane = threadIdx.x;
  float v = wsLogZ[lane] - wsGold[lane];
  #pragma unroll
  for (int off = 32; off; off >>= 1) v += __shfl_xor(v, off);
  if (lane == 0) out[0] = v;
}

extern "C" void kernel_launch(void* const* d_in, const int* in_sizes, int n_in,
                              void* d_out, int out_size, void* d_ws, size_t ws_size,
                              hipStream_t stream) {
  const float* x      = (const float*)d_in[0];
  const int*   mask   = (const int*)  d_in[1];
  const int*   labels = (const int*)  d_in[2];
  const float* W      = (const float*)d_in[3];
  const float* bias   = (const float*)d_in[4];
  const float* trans  = (const float*)d_in[5];
  const float* startv = (const float*)d_in[6];
  const float* endv   = (const float*)d_in[7];

  float* out  = (float*)d_out;
  float* feat = out;
  float* pred = out + PRED_OFF;
  float* loss = out + LOSS_OFF;
  float* wsLogZ = (float*)d_ws;
  float* wsGold = wsLogZ + 64;

  gemm_feat<<<(Bn*Sn)/64, 256, 0, stream>>>(x, W, bias, feat);

  if (ws_size >= WS_NEED) {
    float* vws = (float*)((char*)d_ws + VWS_BYTE_OFF);
    unsigned char* bpw = (unsigned char*)d_ws + BPW_BYTE_OFF;
    crf_scan<<<192, 64, 0, stream>>>(feat, mask, labels, trans, startv, endv, vws, wsLogZ, wsGold);
    bp_kernel<<<512, 256, 0, stream>>>(vws, mask, trans, bpw);
    backtrace_kernel<<<64, 64, 0, stream>>>(vws, bpw, mask, endv, pred);
  } else {
    crf_kernel_fb<<<192, 64, 0, stream>>>(feat, mask, labels, trans, startv, endv, pred, wsLogZ, wsGold);
  }
  loss_reduce<<<1, 64, 0, stream>>>(wsLogZ, wsGold, loss);
}